// Round 14
// baseline (316.730 us; speedup 1.0000x reference)
//
#include <hip/hip_runtime.h>

// Com2Net wavefront kernel, round 15b: f16 dot-product datapath.
// (R15 failed to COMPILE only: cvt_pkrtz returns __fp16x2, fdot2 wants
// _Float16x2 — same bits, different clang types. Fixed with bit_cast.)
// R14's null (pk_fma_f32: half the instructions, identical time) proved the
// binder is FP32 DATAPATH cycles (157.3TF = 1 fma/lane/cyc; pk_f32 = 4cyc).
// The only CDNA instruction that doubles FLOPs/datapath-cyc is the DL dot
// v_dot2_f32_f16 (f16 pair-MAC, f32 accumulate, full rate). Both GEMV layers
// move to fdot2; sigma/state/selects stay f32 (error = input quantization
// only: ~1e-2 worst vs 2.05e-2 threshold). Builtins only (R13 lesson).
//   - L1: a_k = fdot2(w1c_k,{cA,cB}, fdot2(w1x_k,{xa,xb}, b1_k)); comm-part
//     outermost (chain-late). 20 fdot2 vs 40 fma.
//   - L2: 15 fdot2 vs 30 fma, horizontal adds eliminated (f32 scalar accum).
//   - eval: 442 -> 372 cyc issue (16c-trans model); step ~930 -> ~790.
// One risk at a time: WARM stays 48 (bit-identical-proven). Structure =
// R12 (CHUNKS=8, 64-row ring, full-line nontemporal flush, dist-4 prefetch).

#define T_STEPS 1024
#define N_AGENTS 128
#define CHUNKS 8
#define CLEN (T_STEPS / CHUNKS)      // 128 timesteps written per chunk
#define WARM 48                      // discarded warm-up steps (chunks >= 1)
#define RAMP 64                      // wavefront skew ramp
#define USTEPS (CLEN + WARM + RAMP)  // 240 macro-steps (mult of 4)
#define SHIFT ((64 - (WARM & 63)) & 63)  // t0 mod 64 = 16
#define RD_OFF (WARM + 63)           // in-chunk row m ring-read at u=m+RD_OFF
#define ST_OFF (RD_OFF + 4)          // ...and global-stored 4 steps later

typedef float v2f __attribute__((ext_vector_type(2)));
typedef _Float16 v2h __attribute__((ext_vector_type(2)));

// f32x2 -> f16x2 (v_cvt_pkrtz_f16_f32, round-toward-zero, 1 full-rate instr).
// bit_cast bridges clang's __fp16x2 (cvt_pkrtz return) to _Float16x2 (fdot2
// operand) — identical 32-bit layout, zero instructions.
__device__ __forceinline__ v2h pkh(float a, float b) {
    return __builtin_bit_cast(v2h, __builtin_amdgcn_cvt_pkrtz(a, b));
}
// d = a.x*b.x + a.y*b.y + c  (v_dot2_f32_f16: f16 inputs, f32 accumulate)
__device__ __forceinline__ float fdot2(v2h a, v2h b, float c) {
    return __builtin_amdgcn_fdot2(a, b, c, false);
}

// Whole-wave shift-by-1 via DPP. wave_shr1 (0x138): lane i <- lane i-1,
// lane 0 <- 0 (bound_ctrl). wave_shl1 (0x130): lane i <- lane i+1, lane 63 <- 0.
// bound_ctrl zeros are exactly comm[0]/comm[2N+1], which are never written.
__device__ __forceinline__ float wave_shr1(float x) {
    int r = __builtin_amdgcn_update_dpp(0, __builtin_bit_cast(int, x),
                                        0x138, 0xF, 0xF, true);
    return __builtin_bit_cast(float, r);
}
__device__ __forceinline__ float wave_shl1(float x) {
    int r = __builtin_amdgcn_update_dpp(0, __builtin_bit_cast(int, x),
                                        0x130, 0xF, 0xF, true);
    return __builtin_bit_cast(float, r);
}

struct Weights {
    v2h w1x[10], w1c[10];    // f16 pairs {W1[k][0..1]}*S, {W1[k][2..3]}*S
    float b1s[10];           // f32, * 2*log2(e)
    v2h w20h[5], w21h[5], w22h[5];  // f16 pairs of -2*W2 row r (sigma-fold)
    float b20, b21, b22;     // f32 = b2[r] + sum_k W2[r,k]
};

// One S2Net eval. Layer 1 + layer 2 on v_dot2_f32_f16; sigma (sigma-fold +
// paired reciprocal) in f32 exactly as R12. cab is the chain-late operand:
// its fdot2 is outermost.
__device__ __forceinline__ void mlp_eval(const Weights& w, v2h xab,
                                         float cA, float cB,
                                         float& o0, float& o1, float& o2) {
    const v2h cab = pkh(cA, cB);
    float a[10];
#pragma unroll
    for (int k = 0; k < 10; ++k)
        a[k] = fdot2(w.w1c[k], cab, fdot2(w.w1x[k], xab, w.b1s[k]));
    v2h hh[5];
#pragma unroll
    for (int p = 0; p < 5; ++p) {
        float ea = __builtin_amdgcn_exp2f(a[2 * p]);
        float eb = __builtin_amdgcn_exp2f(a[2 * p + 1]);
        float A = ea + 1.f, B = eb + 1.f;
        float rr = __builtin_amdgcn_rcpf(A * B);
        hh[p] = pkh(B * rr, A * rr);   // {sigma(a_2p), sigma(a_2p+1)}
    }
    float s0 = w.b20, s1 = w.b21, s2 = w.b22;
#pragma unroll
    for (int p = 0; p < 5; ++p) {
        s0 = fdot2(w.w20h[p], hh[p], s0);
        s1 = fdot2(w.w21h[p], hh[p], s1);
        s2 = fdot2(w.w22h[p], hh[p], s2);
    }
    o0 = s0; o1 = s1; o2 = s2;
}

__global__ void __launch_bounds__(64, 1)
com2net_wavefront(const float* __restrict__ runs,
                  const float* __restrict__ W1, const float* __restrict__ b1,
                  const float* __restrict__ W2, const float* __restrict__ b2,
                  float* __restrict__ out)
{
    const int blk = blockIdx.x;
    const int r   = blk >> 3;              // run index
    const int c   = blk & (CHUNKS - 1);    // time-chunk index
    const int j   = threadIdx.x;           // lane 0..63, owns agents 2j, 2j+1

    const int wstart = c * CLEN;           // first written timestep
    const int wend   = wstart + CLEN;      // one past last written timestep
    const int t0     = wstart - WARM;      // u=0: t = t0 + u - j
    // Chunk 0 must start EXACTLY at t=0 with comm=0 (the reference init).
    const int slo = (c == 0) ? 0 : -0x40000000;

    // 64-row output ring: slot ((t - wstart) & 63), column j. 32 KiB.
    __shared__ v2f ring[64][N_AGENTS / 2];

    const float S = 2.8853900817779268f;  // 2*log2(e), folded into layer 1
    Weights w;
#pragma unroll
    for (int k = 0; k < 10; ++k) {
        w.w1x[k] = pkh(W1[k * 4 + 0] * S, W1[k * 4 + 1] * S);
        w.w1c[k] = pkh(W1[k * 4 + 2] * S, W1[k * 4 + 3] * S);
        w.b1s[k] = b1[k] * S;
    }
#pragma unroll
    for (int p = 0; p < 5; ++p) {
        w.w20h[p] = pkh(-2.f * W2[0 * 10 + 2 * p], -2.f * W2[0 * 10 + 2 * p + 1]);
        w.w21h[p] = pkh(-2.f * W2[1 * 10 + 2 * p], -2.f * W2[1 * 10 + 2 * p + 1]);
        w.w22h[p] = pkh(-2.f * W2[2 * 10 + 2 * p], -2.f * W2[2 * 10 + 2 * p + 1]);
    }
    float s0 = 0.f, s1 = 0.f, s2 = 0.f;
#pragma unroll
    for (int k = 0; k < 10; ++k) {
        s0 += W2[0 * 10 + k];
        s1 += W2[1 * 10 + k];
        s2 += W2[2 * 10 + k];
    }
    w.b20 = b2[0] + s0; w.b21 = b2[1] + s1; w.b22 = b2[2] + s2;

    const float4* __restrict__ xbase =
        (const float4*)(runs + (size_t)r * T_STEPS * N_AGENTS * 2);
    v2f* __restrict__ obase =
        (v2f*)(out + (size_t)r * T_STEPS * N_AGENTS);

    // Replicated recurrence state; zero-init == warm-up / reference init.
    float c1e = 0.f, c2e = 0.f, c1o = 0.f, c2o = 0.f;

    // Clamped row load (OOB lanes re-read row 0/1023; results discarded by
    // the state guards; loads hit cache).
    auto ldrow = [&](int t) -> float4 {
        int tc = t < 0 ? 0 : t;
        tc = tc > T_STEPS - 1 ? T_STEPS - 1 : tc;
        return xbase[tc * (N_AGENTS / 2) + j];
    };

    // One macro-step. pend carries the ring row read at this unroll slot; it
    // is global-stored when the slot comes around next iteration (~5000 cyc
    // later -> lgkmcnt long satisfied, store off the recurrence chain).
    auto step = [&](int u, const float4& x, v2f& pend) {
        const int t = t0 + u - j;
        const bool supd = (t >= slo) & (t < wend);

        // x inputs quantized to f16 once per step (off the recurrence chain).
        const v2h xe = pkh(x.x, x.y);
        const v2h xo = pkh(x.z, x.w);

        // ---- even phase: agent 2j at t ----
        float c2pv = wave_shr1(c2o);
        float o0e, o1e, o2e;
        mlp_eval(w, xe, c2pv, c1o, o0e, o1e, o2e);
        c1e = supd ? o1e : c1e;
        c2e = supd ? o2e : c2e;

        // ---- odd phase: agent 2j+1 at t ----
        float c1pv = wave_shl1(c1e);
        float o0o, o1o, o2o;
        mlp_eval(w, xo, c2e, c1pv, o0o, o1o, o2o);
        c1o = supd ? o1o : c1o;
        c2o = supd ? o2o : c2o;

        // Store the row this unroll slot ring-read one iteration ago
        // (full-line, lane-contiguous 512B, nontemporal).
        const int mst = u - ST_OFF;
        if ((unsigned)mst < (unsigned)CLEN)
            __builtin_nontemporal_store(
                pend, &obase[(size_t)(wstart + mst) * (N_AGENTS / 2) + j]);

        // Stage this step's outputs: row t0+u-j -> slot (u-j+SHIFT)&63
        // == (in-chunk row)&63.
        ring[(unsigned)(u - j + SHIFT) & 63u][j] = (v2f){o0e, o0o};

        // In-chunk row m = u-RD_OFF just completed (lane 63 wrote it this
        // step); its slot m&63 = (u+SHIFT+1)&63 is overwritten by lane 0 at
        // step u+1 -> read NOW (same-wave DS ops execute in issue order).
        const int mrd = u - RD_OFF;
        if ((unsigned)mrd < (unsigned)CLEN)
            pend = ring[(unsigned)(u + SHIFT + 1) & 63u][j];
    };

    // Distance-4 register prefetch pipeline, manual unroll-by-4.
    float4 X0 = ldrow(t0 + 0 - j);
    float4 X1 = ldrow(t0 + 1 - j);
    float4 X2 = ldrow(t0 + 2 - j);
    float4 X3 = ldrow(t0 + 3 - j);

    v2f p0 = (v2f){0.f, 0.f}, p1 = p0, p2 = p0, p3 = p0;

    for (int u = 0; u < USTEPS; u += 4) {   // 240 = 4*60 iters
        step(u + 0, X0, p0); X0 = ldrow(t0 + u + 4 - j);
        step(u + 1, X1, p1); X1 = ldrow(t0 + u + 5 - j);
        step(u + 2, X2, p2); X2 = ldrow(t0 + u + 6 - j);
        step(u + 3, X3, p3); X3 = ldrow(t0 + u + 7 - j);
    }

    // Epilogue: rows read in the final iteration (u=236..238 -> rows
    // CLEN-3..CLEN-1) are still in p0..p2; p3's final read was gated off.
    __builtin_nontemporal_store(
        p0, &obase[(size_t)(wstart + CLEN - 3) * (N_AGENTS / 2) + j]);
    __builtin_nontemporal_store(
        p1, &obase[(size_t)(wstart + CLEN - 2) * (N_AGENTS / 2) + j]);
    __builtin_nontemporal_store(
        p2, &obase[(size_t)(wstart + CLEN - 1) * (N_AGENTS / 2) + j]);
}

extern "C" void kernel_launch(void* const* d_in, const int* in_sizes, int n_in,
                              void* d_out, int out_size, void* d_ws, size_t ws_size,
                              hipStream_t stream) {
    const float* runs = (const float*)d_in[0];
    const float* W1   = (const float*)d_in[1];
    const float* b1   = (const float*)d_in[2];
    const float* W2   = (const float*)d_in[3];
    const float* b2   = (const float*)d_in[4];
    float* out = (float*)d_out;

    const int R = 128;
    com2net_wavefront<<<R * CHUNKS, 64, 0, stream>>>(runs, W1, b1, W2, b2, out);
}